// Round 9
// baseline (230.643 us; speedup 1.0000x reference)
//
#include <hip/hip_runtime.h>

// FlowNet correlation: out[b, dy*9+dx, y, x] = (1/256) sum_c x1[b,c,y,x] * x2[b,c,y+dy-4,x+dx-4]
// B=4 C=256 H=W=128, 9x9 displacements, zero padding.
//
// Round-13: CLEAN TLP experiment. r4 kernel geometry byte-for-byte
// (192 thr, CC=4, RSC=48, gy=lane>>2, 27648B LDS, 2.65M conflicts) with the
// channel dim split 2-way ACROSS BLOCKS: grid 768 -> 1536, partials in d_ws,
// + r12's validated reduce kernel. Per CU: 5 resident blocks (LDS 138KB) =
// 15 waves/CU = 3.75 waves/SIMD vs 2.25.
// Why: r4..r12 ledger shows the structure pinned at 102us across CC, px/lane,
// barrier flavor, prefetch order; per-wave VALU issue ~490cyc/chunk vs
// ~3800cyc wall -> pure TLP deficit. All prior TLP probes were confounded
// (r5 spill, r7 conflicts, r8 coalescing); this one changes ONLY wave count.
// Swizzle: h-bit at t'>>8 -> h-sibling bids differ by 768 = 0 mod 8, so the
// g-sibling same-XCD property (bids +8/+16, same q) is preserved; h-siblings
// share no data (disjoint channels). Fallback (no ws): nh=1 == r4 exactly.

#define MD 4
constexpr int Bc = 4, Cc = 256, Hc = 128, Wc = 128;
constexpr int HW = Hc * Wc;
constexpr int TH = 16, TW = 16;
constexpr int NDY = 3;                  // dy per d-group (one per wave)
constexpr int CC = 4;                   // channels per chunk
constexpr int SROWS = TH + NDY - 1;     // 18 staged rows
constexpr int SCOLS = TW + 2 * MD;      // 24 staged cols
constexpr int RSC = 48;                 // padded row stride (dw), 48%32==16 -> clean b128
constexpr int CH_STRIDE = SROWS * RSC;  // 864 dw per channel
constexpr int BUF_DW = CC * CH_STRIDE;  // 3456 dw per buffer
constexpr int NF4 = CC * SROWS * (SCOLS / 4);  // 432 float4 staging slots
constexpr int NTHR = 192;
constexpr int NSLOT = 3;                // ceil(432/192)
constexpr long long OUTN = (long long)Bc * 81 * HW;   // 5,308,416 floats

__global__ __launch_bounds__(NTHR, 4)
void corr_kernel(const float* __restrict__ x1, const float* __restrict__ x2,
                 float* __restrict__ dst, int nh, float scl)
{
    __shared__ float stg[2 * BUF_DW];   // 27648 B

    const int tid  = threadIdx.x;
    const int w    = tid >> 6;          // wave id = local dy
    const int lane = tid & 63;
    const int gy   = lane >> 2;         // 0..15 tile row
    const int gx   = lane & 3;          // 0..3  col-group (4 px each)

    // ---- XCD-aware swizzle: g-siblings (same tile) get bids {b, b+8, b+16}
    //      (same q -> same XCD under bid%8). h-bit lives at t'>>8: h-sibling
    //      bids differ by 768 = 0 mod 8 (placement-neutral; no shared data). ----
    const int bid  = blockIdx.x;
    const int q    = bid / 24;
    const int r    = bid - q * 24;
    const int g    = r >> 3;            // d-group 0..2
    const int tp   = q * 8 + (r & 7);   // t' in [0, 256*nh)
    const int hh   = (nh == 2) ? (tp >> 8) : 0;   // channel half
    const int t    = tp & 255;          // tile index 0..255
    const int tx = t & 7;
    const int ty = (t >> 3) & 7;
    const int bb = t >> 6;
    const int x0 = tx * TW, y0 = ty * TH;
    const int rowbase = y0 + 3 * g - MD;   // global y of staged row 0
    const int CN = Cc / nh;                // channels this block
    const int NK = CN / CC;                // chunks (32 split / 64 fallback)
    const int c0 = hh * CN;

    // ---- hoisted staging slot descriptors (fixed per thread across chunks) ----
    int  s_goff[NSLOT], s_loff[NSLOT];
    bool s_val[NSLOT], s_act[NSLOT];
    #pragma unroll
    for (int s = 0; s < NSLOT; ++s) {
        int idx = tid + s * NTHR;
        bool active = idx < NF4;
        int i2  = active ? idx : 0;
        int cl  = i2 / (SROWS * 6);
        int rem = i2 - cl * (SROWS * 6);
        int rr  = rem / 6;
        int gc  = rem - rr * 6;
        int yy  = rowbase + rr;
        int xx  = x0 - 4 + 4 * gc;          // multiple of 4: float4 all-valid or all-invalid
        s_act[s]  = active;
        s_val[s]  = active && ((unsigned)yy < (unsigned)Hc) && ((unsigned)xx < (unsigned)(Wc - 3));
        s_goff[s] = cl * HW + yy * Wc + xx;
        s_loff[s] = cl * CH_STRIDE + rr * RSC + 4 * gc;
    }

    const float* x2b = x2 + ((size_t)bb * Cc + c0) * HW;
    const float* x1b = x1 + ((size_t)bb * Cc + c0) * HW + (y0 + gy) * Wc + x0 + 4 * gx;

    float acc[9][4];
    #pragma unroll
    for (int dx = 0; dx < 9; ++dx)
        #pragma unroll
        for (int p = 0; p < 4; ++p) acc[dx][p] = 0.f;

    const float4 f40 = make_float4(0.f, 0.f, 0.f, 0.f);
    float4 nf[NSLOT];

    // ---- prologue: stage chunk 0 into buffer 0 ----
    #pragma unroll
    for (int s = 0; s < NSLOT; ++s) {
        nf[s] = f40;
        if (s_val[s]) nf[s] = *(const float4*)(x2b + s_goff[s]);
    }
    #pragma unroll
    for (int s = 0; s < NSLOT; ++s)
        if (s_act[s]) *(float4*)(&stg[s_loff[s]]) = nf[s];

    for (int k = 0; k < NK; ++k) {
        const int pb = k & 1;
        // issue global x2 prefetch for chunk k+1 (r4-validated ordering)
        if (k + 1 < NK) {
            const int gof = (k + 1) * CC * HW;
            #pragma unroll
            for (int s = 0; s < NSLOT; ++s) {
                nf[s] = f40;
                if (s_val[s]) nf[s] = *(const float4*)(x2b + gof + s_goff[s]);
            }
        }
        __syncthreads();   // chunk k's buffer fully written; prev buffer's readers done
        // ---- compute chunk k (x1 loaded inline: L1/L2 hits, no reg pressure) ----
        #pragma unroll
        for (int cl = 0; cl < CC; ++cl) {
            const int c = k * CC + cl;
            const float4 a4 = *(const float4*)(x1b + (size_t)c * HW);
            const float* rowp = &stg[pb * BUF_DW + cl * CH_STRIDE + (gy + w) * RSC + 4 * gx];
            const float4 q0 = *(const float4*)(rowp);
            const float4 q1 = *(const float4*)(rowp + 4);
            const float4 q2 = *(const float4*)(rowp + 8);
            const float v[12] = {q0.x, q0.y, q0.z, q0.w,
                                 q1.x, q1.y, q1.z, q1.w,
                                 q2.x, q2.y, q2.z, q2.w};
            const float a[4] = {a4.x, a4.y, a4.z, a4.w};
            #pragma unroll
            for (int dx = 0; dx < 9; ++dx)
                #pragma unroll
                for (int p = 0; p < 4; ++p)
                    acc[dx][p] += a[p] * v[dx + p];
        }
        // ---- commit prefetched chunk k+1 (after this iter's barrier: safe) ----
        if (k + 1 < NK) {
            const int lb = ((k + 1) & 1) * BUF_DW;
            #pragma unroll
            for (int s = 0; s < NSLOT; ++s)
                if (s_act[s]) *(float4*)(&stg[lb + s_loff[s]]) = nf[s];
        }
    }

    // ---- epilogue: scale (1.0 for partials, 1/C for fallback) and store ----
    float* ob = dst + (size_t)hh * OUTN
              + (((size_t)bb * 81 + (3 * g + w) * 9) * Hc + (y0 + gy)) * Wc + x0 + 4 * gx;
    #pragma unroll
    for (int dx = 0; dx < 9; ++dx) {
        float4 st = make_float4(acc[dx][0] * scl, acc[dx][1] * scl,
                                acc[dx][2] * scl, acc[dx][3] * scl);
        *(float4*)(ob + dx * HW) = st;
    }
}

// out = (wsA + wsB) * inv, float4-wise grid-stride. ~64 MB traffic, BW-bound.
__global__ __launch_bounds__(256)
void reduce_kernel(const float* __restrict__ ws, float* __restrict__ out, float scl)
{
    const long long N4 = OUTN / 4;
    const float4* pa = (const float4*)ws;
    const float4* pb = (const float4*)(ws + OUTN);
    float4* po = (float4*)out;
    long long i = (long long)blockIdx.x * 256 + threadIdx.x;
    const long long step = (long long)gridDim.x * 256;
    for (; i < N4; i += step) {
        float4 a = pa[i], b = pb[i];
        po[i] = make_float4((a.x + b.x) * scl, (a.y + b.y) * scl,
                            (a.z + b.z) * scl, (a.w + b.w) * scl);
    }
}

extern "C" void kernel_launch(void* const* d_in, const int* in_sizes, int n_in,
                              void* d_out, int out_size, void* d_ws, size_t ws_size,
                              hipStream_t stream) {
    const float* x1 = (const float*)d_in[0];
    const float* x2 = (const float*)d_in[1];
    float* out = (float*)d_out;
    const float inv = 1.0f / (float)Cc;
    const size_t need = (size_t)(2 * OUTN) * sizeof(float);   // 42.5 MB partials
    if (d_ws != nullptr && ws_size >= need) {
        float* ws = (float*)d_ws;
        dim3 grid(24 * 64), block(NTHR);          // 1536 blocks: 3g x 256 tiles x 2h
        corr_kernel<<<grid, block, 0, stream>>>(x1, x2, ws, 2, 1.0f);
        reduce_kernel<<<dim3(2048), dim3(256), 0, stream>>>(ws, out, inv);
    } else {
        dim3 grid(24 * 32), block(NTHR);          // 768 blocks == r4 exactly
        corr_kernel<<<grid, block, 0, stream>>>(x1, x2, out, 1, inv);
    }
}